// Round 5
// baseline (1722.818 us; speedup 1.0000x reference)
//
#include <hip/hip_runtime.h>
#include <hip/hip_bf16.h>
#include <stdint.h>

// B=8192, D_IN=1024, D_HID=4096, D_OUT=1024, E=8
#define BB 8192
#define DIN 1024
#define DHID 4096
#define DOUT 1024
#define NEXP 8
#define GH_N 2048  // D_HID/2

typedef __attribute__((ext_vector_type(8))) __bf16 bf16x8;
typedef __attribute__((ext_vector_type(4))) float f32x4;

__device__ inline unsigned short f2bf(float f) {
  unsigned u = __builtin_bit_cast(unsigned, f);
  u = (u + 0x7FFFu + ((u >> 16) & 1u)) >> 16;
  return (unsigned short)u;
}
__device__ inline float b2f(unsigned short s) {
  return __builtin_bit_cast(float, (unsigned)s << 16);
}

// ---------------- elementwise f32 -> bf16 ----------------
__global__ void cvt_f32_bf16(const float* __restrict__ in,
                             unsigned short* __restrict__ out, int n4) {
  int i = blockIdx.x * blockDim.x + threadIdx.x;
  if (i >= n4) return;
  float4 v = ((const float4*)in)[i];
  ushort4 o;
  o.x = f2bf(v.x); o.y = f2bf(v.y); o.z = f2bf(v.z); o.w = f2bf(v.w);
  ((ushort4*)out)[i] = o;
}

// ---------------- transpose + convert: in[R][C] f32 -> out[C][R] bf16 ----------------
__device__ inline void tr_tile(const float* __restrict__ in,
                               unsigned short* __restrict__ out, int R, int C,
                               int bx, int by) {
  __shared__ float tile[32][33];
  int c0 = bx * 32, r0 = by * 32;
  int tx = threadIdx.x & 31, ty = threadIdx.x >> 5;
#pragma unroll
  for (int i = 0; i < 4; ++i)
    tile[ty + i * 8][tx] = in[(size_t)(r0 + ty + i * 8) * C + c0 + tx];
  __syncthreads();
#pragma unroll
  for (int i = 0; i < 4; ++i)
    out[(size_t)(c0 + ty + i * 8) * R + r0 + tx] = f2bf(tile[tx][ty + i * 8]);
}

__global__ void transpose_cvt(const float* __restrict__ in,
                              unsigned short* __restrict__ out, int R, int C) {
  tr_tile(in, out, R, C, blockIdx.x, blockIdx.y);
}

// fused per-expert: W1 [1024][4096]->w1T and W2 [4096][1024]->w2T
__global__ void transpose_cvt2(const float* __restrict__ w1,
                               unsigned short* __restrict__ w1T,
                               const float* __restrict__ w2,
                               unsigned short* __restrict__ w2T) {
  int b = blockIdx.x;
  if (b < 4096) {
    tr_tile(w1, w1T, DIN, DHID, b & 127, b >> 7);
  } else {
    b -= 4096;
    tr_tile(w2, w2T, DHID, DOUT, b & 31, b >> 5);
  }
}

// ---------------- async global->LDS 16B ----------------
__device__ inline void gload16(const void* g, void* l) {
  __builtin_amdgcn_global_load_lds(
      (const __attribute__((address_space(1))) void*)g,
      (__attribute__((address_space(3))) void*)l, 16, 0, 0);
}

template <int N>
__device__ inline void waitv() {
  if constexpr (N == 0) asm volatile("s_waitcnt vmcnt(0)" ::: "memory");
  else if constexpr (N == 1) asm volatile("s_waitcnt vmcnt(1)" ::: "memory");
  else if constexpr (N == 2) asm volatile("s_waitcnt vmcnt(2)" ::: "memory");
  else if constexpr (N == 3) asm volatile("s_waitcnt vmcnt(3)" ::: "memory");
  else if constexpr (N == 4) asm volatile("s_waitcnt vmcnt(4)" ::: "memory");
  else asm volatile("s_waitcnt vmcnt(0)" ::: "memory");
}
__device__ inline void waitlgkm0() {
  asm volatile("s_waitcnt lgkmcnt(0)" ::: "memory");
  __builtin_amdgcn_sched_barrier(0);
}
__device__ inline bf16x8 ldr(const char* p) { return *(const bf16x8*)p; }

// ---------------- 4-phase quadrant GEMM: C = A[M,K]*Bt[N,K]^T ----------------
// BN=256 fixed. 8 waves (2M x 4N), BK=64, 2 LDS buffers. See r4 notes.
// EPI 0: outb = bf16(relu(acc+bias[col])); optional piggyback combine (bn==0):
//        outf[r][c] (+)= gates[r*8+eidx]*(comb0+comb1+combBias)  over 256rx1024c
// EPI 1: outf = (accum? outf:0) + gates[row*8+eidx]*(acc+bias[col])   (fallback)
// EPI 2: split-K partial: ks=swz&1, A/Bt k-offset ks*K, outf += ks*M*N; raw acc.
template <int BM, int EPI>
__global__ __launch_bounds__(512, 2)
void gemmP(const unsigned short* __restrict__ A, int lda,
           const unsigned short* __restrict__ Bt, int ldb,
           int M, int N, int K,
           const float* __restrict__ bias,
           unsigned short* __restrict__ outb,
           float* __restrict__ outf,
           const float* __restrict__ gates, int eidx, int accum,
           const float* __restrict__ comb0, const float* __restrict__ comb1,
           const float* __restrict__ combBias) {
  constexpr int BN = 256;
  constexpr int WROWS = BM / 2;
  constexpr int RM = WROWS / 16;
  constexpr int HM = RM / 2;
  constexpr int ABYTES = BM * 128;
  constexpr int BBYTES = BN * 128;
  constexpr int AUN = BM / 64;
  constexpr int WS = (BM == 256) ? 4 : 3;
  constexpr int W0L = (BM == 256) ? 2 : 1;

  __shared__ char lds[2 * (ABYTES + BBYTES)];
  char* Als = lds;
  char* Bls = lds + 2 * ABYTES;

  const int t = threadIdx.x;
  const int lane = t & 63;
  const int wid = t >> 6;
  const int wm = wid >> 2;
  const int wn = wid & 3;
  const int l15 = lane & 15, lg = lane >> 4;

  // bijective XCD swizzle (all grids %8==0)
  const int nwg = gridDim.x, flat = blockIdx.x;
  const int swz = (flat & 7) * (nwg >> 3) + (flat >> 3);
  int ks = 0, tid = swz;
  if (EPI == 2) { ks = swz & 1; tid = swz >> 1; }
  const int nbn = N >> 8;
  const int bn = tid % nbn, bm = tid / nbn;
  const int m0 = bm * BM, n0 = bn * BN;
  const int kbase = ks * K;
  if (EPI == 2) outf += (size_t)ks * ((size_t)M * N);

  // ---- stage source pointers (XOR chunk swizzle) ----
  const int prow = t >> 3;
  const int cOff = ((t & 7) ^ (prow & 7)) * 8;
  const unsigned short* aP[AUN];
  const unsigned short* bP[4];
#pragma unroll
  for (int u = 0; u < AUN; ++u) {
    int p = u * 64 + prow;
    int g;
    if (BM == 256) g = ((p >> 6) & 1) * 128 + ((p >> 7) & 1) * 64 + (p & 63);
    else           g = ((p >> 5) & 1) * 64  + ((p >> 6) & 1) * 32 + (p & 31);
    aP[u] = A + (size_t)(m0 + g) * lda + kbase + cOff;
  }
#pragma unroll
  for (int u = 0; u < 4; ++u) {
    int p = u * 64 + prow;
    int g = ((p >> 5) & 3) * 64 + ((p >> 7) & 1) * 32 + (p & 31);
    bP[u] = Bt + (size_t)(n0 + g) * ldb + kbase + cOff;
  }
  const int ldst = t * 16;

  // ---- LDS read bases ----
  const int slot0 = ((lg) ^ (l15 & 7)) * 16;
  const int slot1 = ((4 + lg) ^ (l15 & 7)) * 16;
  const int aRB0 = (0 * (BM / 2) + wm * (WROWS / 2) + l15) * 128;
  const int aRB1 = (1 * (BM / 2) + wm * (WROWS / 2) + l15) * 128;
  const int bCB0 = (0 * (BN / 2) + wn * 32 + l15) * 128;
  const int bCB1 = (1 * (BN / 2) + wn * 32 + l15) * 128;

  f32x4 acc[RM][4];
  const f32x4 zero = {0.f, 0.f, 0.f, 0.f};
#pragma unroll
  for (int i = 0; i < RM; ++i)
#pragma unroll
    for (int j = 0; j < 4; ++j) acc[i][j] = zero;

  bf16x8 ar[HM][2], bc0[2][2], bc1[2][2];

  const int NT = K >> 6;

  // ---- prologue ----
  {
    gload16(bP[0], Bls + 0 * 8192 + ldst);
    gload16(bP[1], Bls + 1 * 8192 + ldst);
    gload16(aP[0], Als + 0 * 8192 + ldst);
    if (AUN == 4) gload16(aP[1], Als + 1 * 8192 + ldst);
    gload16(bP[2], Bls + 2 * 8192 + ldst);
    gload16(bP[3], Bls + 3 * 8192 + ldst);
    if (AUN == 4) {
      gload16(aP[2], Als + 2 * 8192 + ldst);
      gload16(aP[3], Als + 3 * 8192 + ldst);
    } else {
      gload16(aP[1], Als + 1 * 8192 + ldst);
    }
  }
  waitv<WS>();
  __builtin_amdgcn_s_barrier();

  for (int T = 0; T < NT; ++T) {
    const int buf = T & 1;
    const char* Ab = Als + buf * ABYTES;
    const char* Bb = Bls + buf * BBYTES;
    char* An = Als + (buf ^ 1) * ABYTES;
    char* Bn = Bls + (buf ^ 1) * BBYTES;
    const bool stg = (T + 1 < NT);
    const int kn = (T + 1) << 6;

    // ph0
#pragma unroll
    for (int f = 0; f < HM; ++f) {
      ar[f][0] = ldr(Ab + aRB0 + f * 2048 + slot0);
      ar[f][1] = ldr(Ab + aRB0 + f * 2048 + slot1);
    }
#pragma unroll
    for (int c = 0; c < 2; ++c) {
      bc0[c][0] = ldr(Bb + bCB0 + c * 2048 + slot0);
      bc0[c][1] = ldr(Bb + bCB0 + c * 2048 + slot1);
    }
    if (stg) {
      gload16(bP[0] + kn, Bn + 0 * 8192 + ldst);
      gload16(bP[1] + kn, Bn + 1 * 8192 + ldst);
    }
    __builtin_amdgcn_s_barrier();
    waitlgkm0();
    __builtin_amdgcn_s_setprio(1);
#pragma unroll
    for (int ksl = 0; ksl < 2; ++ksl)
#pragma unroll
      for (int f = 0; f < HM; ++f)
#pragma unroll
        for (int c = 0; c < 2; ++c)
          acc[f][c] = __builtin_amdgcn_mfma_f32_16x16x32_bf16(
              ar[f][ksl], bc0[c][ksl], acc[f][c], 0, 0, 0);
    __builtin_amdgcn_s_setprio(0);
    if (stg) waitv<WS>(); else waitv<W0L>();
    __builtin_amdgcn_s_barrier();

    // ph1
#pragma unroll
    for (int c = 0; c < 2; ++c) {
      bc1[c][0] = ldr(Bb + bCB1 + c * 2048 + slot0);
      bc1[c][1] = ldr(Bb + bCB1 + c * 2048 + slot1);
    }
    if (stg) {
      gload16(aP[0] + kn, An + 0 * 8192 + ldst);
      if (AUN == 4) gload16(aP[1] + kn, An + 1 * 8192 + ldst);
    }
    __builtin_amdgcn_s_barrier();
    waitlgkm0();
    __builtin_amdgcn_s_setprio(1);
#pragma unroll
    for (int ksl = 0; ksl < 2; ++ksl)
#pragma unroll
      for (int f = 0; f < HM; ++f)
#pragma unroll
        for (int c = 0; c < 2; ++c)
          acc[f][2 + c] = __builtin_amdgcn_mfma_f32_16x16x32_bf16(
              ar[f][ksl], bc1[c][ksl], acc[f][2 + c], 0, 0, 0);
    __builtin_amdgcn_s_setprio(0);
    if (stg) waitv<WS>(); else waitv<0>();
    __builtin_amdgcn_s_barrier();

    // ph2
#pragma unroll
    for (int f = 0; f < HM; ++f) {
      ar[f][0] = ldr(Ab + aRB1 + f * 2048 + slot0);
      ar[f][1] = ldr(Ab + aRB1 + f * 2048 + slot1);
    }
    if (stg) {
      gload16(bP[2] + kn, Bn + 2 * 8192 + ldst);
      gload16(bP[3] + kn, Bn + 3 * 8192 + ldst);
    }
    __builtin_amdgcn_s_barrier();
    waitlgkm0();
    __builtin_amdgcn_s_setprio(1);
#pragma unroll
    for (int ksl = 0; ksl < 2; ++ksl)
#pragma unroll
      for (int f = 0; f < HM; ++f)
#pragma unroll
        for (int c = 0; c < 2; ++c)
          acc[HM + f][2 + c] = __builtin_amdgcn_mfma_f32_16x16x32_bf16(
              ar[f][ksl], bc1[c][ksl], acc[HM + f][2 + c], 0, 0, 0);
    __builtin_amdgcn_s_setprio(0);
    __builtin_amdgcn_s_barrier();

    // ph3
    if (stg) {
      if (AUN == 4) {
        gload16(aP[2] + kn, An + 2 * 8192 + ldst);
        gload16(aP[3] + kn, An + 3 * 8192 + ldst);
      } else {
        gload16(aP[1] + kn, An + 1 * 8192 + ldst);
      }
    }
    __builtin_amdgcn_s_barrier();
    __builtin_amdgcn_s_setprio(1);
#pragma unroll
    for (int ksl = 0; ksl < 2; ++ksl)
#pragma unroll
      for (int f = 0; f < HM; ++f)
#pragma unroll
        for (int c = 0; c < 2; ++c)
          acc[HM + f][c] = __builtin_amdgcn_mfma_f32_16x16x32_bf16(
              ar[f][ksl], bc0[c][ksl], acc[HM + f][c], 0, 0, 0);
    __builtin_amdgcn_s_setprio(0);
    if (stg) waitv<WS>();
    __builtin_amdgcn_s_barrier();
  }

  // ---- epilogue: D row = lg*4 + reg, col = l15 ----
  const int rb = m0 + wm * WROWS + (lg << 2);
  const int cb = n0 + wn * 64 + l15;
  if (EPI == 0) {
#pragma unroll
    for (int fg = 0; fg < RM; ++fg) {
#pragma unroll
      for (int j = 0; j < 4; ++j) {
        int col = cb + j * 16;
        float bv = bias[col];
#pragma unroll
        for (int r = 0; r < 4; ++r) {
          int row = rb + fg * 16 + r;
          float v = acc[fg][j][r] + bv;
          outb[(size_t)row * N + col] = f2bf(fmaxf(v, 0.f));
        }
      }
    }
    // piggyback combine for the PREVIOUS expert's split-K partials
    if (comb0 != nullptr && bn == 0) {
      for (int i = 0; i < 128; ++i) {
        int f = t + i * 512;          // f4 index in 256x256
        int r = f >> 8, c4 = f & 255;
        size_t ro = (size_t)(m0 + r);
        float g = gates[ro * NEXP + eidx];
        float4 a = ((const float4*)(comb0 + ro * DOUT))[c4];
        float4 b = ((const float4*)(comb1 + ro * DOUT))[c4];
        float4 bb = ((const float4*)combBias)[c4];
        float4 o;
        o.x = g * (a.x + b.x + bb.x);
        o.y = g * (a.y + b.y + bb.y);
        o.z = g * (a.z + b.z + bb.z);
        o.w = g * (a.w + b.w + bb.w);
        if (accum) {
          float4 p = ((const float4*)(outf + ro * DOUT))[c4];
          o.x += p.x; o.y += p.y; o.z += p.z; o.w += p.w;
        }
        ((float4*)(outf + ro * DOUT))[c4] = o;
      }
    }
  } else if (EPI == 1) {
#pragma unroll
    for (int fg = 0; fg < RM; ++fg) {
      float g[4];
#pragma unroll
      for (int r = 0; r < 4; ++r)
        g[r] = gates[(size_t)(rb + fg * 16 + r) * NEXP + eidx];
#pragma unroll
      for (int j = 0; j < 4; ++j) {
        int col = cb + j * 16;
        float bv = bias[col];
#pragma unroll
        for (int r = 0; r < 4; ++r) {
          size_t o = (size_t)(rb + fg * 16 + r) * N + col;
          float v = (acc[fg][j][r] + bv) * g[r];
          outf[o] = accum ? outf[o] + v : v;
        }
      }
    }
  } else {  // EPI == 2: raw partial
#pragma unroll
    for (int fg = 0; fg < RM; ++fg) {
#pragma unroll
      for (int j = 0; j < 4; ++j) {
        int col = cb + j * 16;
#pragma unroll
        for (int r = 0; r < 4; ++r) {
          size_t o = (size_t)(rb + fg * 16 + r) * N + col;
          outf[o] = acc[fg][j][r];
        }
      }
    }
  }
}

// ---------------- standalone combine (last expert) ----------------
__global__ void combine_k(const float* __restrict__ p0,
                          const float* __restrict__ p1,
                          const float* __restrict__ bias,
                          const float* __restrict__ gates, int eidx,
                          float* __restrict__ outC) {
  int i = blockIdx.x * blockDim.x + threadIdx.x;  // f4 index over 8192*256
  int r = i >> 8, c4 = i & 255;
  float g = gates[(size_t)r * NEXP + eidx];
  float4 a = ((const float4*)(p0 + (size_t)r * DOUT))[c4];
  float4 b = ((const float4*)(p1 + (size_t)r * DOUT))[c4];
  float4 bb = ((const float4*)bias)[c4];
  float4 p = ((const float4*)(outC + (size_t)r * DOUT))[c4];
  float4 o;
  o.x = p.x + g * (a.x + b.x + bb.x);
  o.y = p.y + g * (a.y + b.y + bb.y);
  o.z = p.z + g * (a.z + b.z + bb.z);
  o.w = p.w + g * (a.w + b.w + bb.w);
  ((float4*)(outC + (size_t)r * DOUT))[c4] = o;
}

// ---------------- gating head v2 ----------------
__global__ __launch_bounds__(512)
void gating_head2(const unsigned short* __restrict__ gh,
                  const float* __restrict__ gW2,
                  const float* __restrict__ gb2,
                  float* __restrict__ gws,
                  float* __restrict__ g1,
                  float* __restrict__ g2) {
  __shared__ float wT[8][2048];
  const int t = threadIdx.x;
  for (int idx = t; idx < 16384; idx += 512) {
    wT[idx & 7][idx >> 3] = gW2[idx];
  }
  __syncthreads();
  const int wid = t >> 6, lane = t & 63;
  const int row = blockIdx.x * 8 + wid;
  const unsigned short* ghr = gh + (size_t)row * 2048;
  float s[8] = {0.f, 0.f, 0.f, 0.f, 0.f, 0.f, 0.f, 0.f};
#pragma unroll
  for (int j = 0; j < 8; ++j) {
    int k4 = lane + 64 * j;
    ushort4 hv = ((const ushort4*)ghr)[k4];
    float h0 = b2f(hv.x), h1 = b2f(hv.y), h2 = b2f(hv.z), h3 = b2f(hv.w);
#pragma unroll
    for (int e = 0; e < 8; ++e) {
      float4 w = ((const float4*)&wT[e][0])[k4];
      s[e] += h0 * w.x + h1 * w.y + h2 * w.z + h3 * w.w;
    }
  }
#pragma unroll
  for (int e = 0; e < 8; ++e)
#pragma unroll
    for (int off = 1; off < 64; off <<= 1) s[e] += __shfl_xor(s[e], off, 64);
  if (lane == 0) {
    float l[8], m = -1e30f;
#pragma unroll
    for (int e = 0; e < 8; ++e) {
      l[e] = s[e] + gb2[e];
      m = fmaxf(m, l[e]);
    }
    float sum = 0.f;
#pragma unroll
    for (int e = 0; e < 8; ++e) {
      l[e] = expf(l[e] - m);
      sum += l[e];
    }
    float inv = 1.f / sum;
#pragma unroll
    for (int e = 0; e < 8; ++e) {
      float gv = l[e] * inv;
      gws[(size_t)row * 8 + e] = gv;
      g1[(size_t)row * 8 + e] = gv;
      g2[(size_t)row * 8 + e] = gv;
    }
  }
}

extern "C" void kernel_launch(void* const* d_in, const int* in_sizes, int n_in,
                              void* d_out, int out_size, void* d_ws,
                              size_t ws_size, hipStream_t stream) {
  (void)in_sizes; (void)n_in; (void)out_size;
  const float* x   = (const float*)d_in[0];
  const float* gW1 = (const float*)d_in[1];
  const float* gb1 = (const float*)d_in[2];
  const float* gW2 = (const float*)d_in[3];
  const float* gb2 = (const float*)d_in[4];
  const float* eW1 = (const float*)d_in[5];
  const float* eb1 = (const float*)d_in[6];
  const float* eW2 = (const float*)d_in[7];
  const float* eb2 = (const float*)d_in[8];

  float* outC  = (float*)d_out;                       // [8192,1024]
  float* outG1 = outC + (size_t)BB * DOUT;            // [8192,8]
  float* outG2 = outG1 + (size_t)BB * NEXP;           // [8192,8]

  char* ws = (char*)d_ws;
  // layout (bytes):
  unsigned short* xb   = (unsigned short*)(ws);                  // 16 MB
  float*          gat  = (float*)(ws + 16777216);                // 256 KB
  unsigned short* w1T  = (unsigned short*)(ws + 17039360);       // 8 MB
  unsigned short* w2T  = (unsigned short*)(ws + 25427968);       // 8 MB
  unsigned short* hbuf = (unsigned short*)(ws + 33816576);       // 64 MB
  unsigned short* gh   = (unsigned short*)(ws + 100925440);      // 32 MB (pre-loop)
  unsigned short* gW1T = (unsigned short*)(ws + 134479872);      // 4 MB (pre-loop)
  float*          p0   = (float*)(ws + 100925440);               // 32 MB (alias gh)
  float*          p1   = (float*)(ws + 134479872);               // 32 MB -> end 168,034,304
  const bool splitk = ws_size >= (size_t)168034304;

  cvt_f32_bf16<<<(BB * DIN / 4) / 256, 256, 0, stream>>>(x, xb, BB * DIN / 4);
  transpose_cvt<<<dim3(GH_N / 32, DIN / 32), 256, 0, stream>>>(gW1, gW1T, DIN, GH_N);
  // gating GEMM: gh = relu(x @ gW1 + gb1)   grid 32*8=256
  gemmP<256, 0><<<dim3((BB / 256) * (GH_N / 256)), 512, 0, stream>>>(
      xb, DIN, gW1T, DIN, BB, GH_N, DIN, gb1, gh, nullptr, nullptr, 0, 0,
      nullptr, nullptr, nullptr);
  gating_head2<<<BB / 8, 512, 0, stream>>>(gh, gW2, gb2, gat, outG1, outG2);

  for (int e = 0; e < NEXP; ++e) {
    transpose_cvt2<<<8192, 256, 0, stream>>>(
        eW1 + (size_t)e * DIN * DHID, w1T, eW2 + (size_t)e * DHID * DOUT, w2T);
    // G1: h = relu(x @ eW1_e + eb1_e)   grid 32*16=512
    // piggyback: combine expert e-1 partials into outC (splitk path)
    const bool comb = splitk && (e > 0);
    gemmP<256, 0><<<dim3((BB / 256) * (DHID / 256)), 512, 0, stream>>>(
        xb, DIN, w1T, DIN, BB, DHID, DIN, eb1 + (size_t)e * DHID, hbuf, outC,
        gat, e - 1, (e - 1) > 0 ? 1 : 0,
        comb ? p0 : nullptr, p1, eb2 + (size_t)(e > 0 ? e - 1 : 0) * DOUT);
    if (splitk) {
      // G2 split-K: partials p0,p1   grid 32*4*2=256 (full chip, fat 256^2)
      gemmP<256, 2><<<dim3((BB / 256) * (DOUT / 256) * 2), 512, 0, stream>>>(
          hbuf, DHID, w2T, DHID, BB, DOUT, DHID / 2, nullptr, nullptr, p0,
          nullptr, 0, 0, nullptr, nullptr, nullptr);
    } else {
      gemmP<128, 1><<<dim3((BB / 128) * (DOUT / 256)), 512, 0, stream>>>(
          hbuf, DHID, w2T, DHID, BB, DOUT, DHID, eb2 + (size_t)e * DOUT,
          nullptr, outC, gat, e, e > 0 ? 1 : 0, nullptr, nullptr, nullptr);
    }
  }
  if (splitk) {
    // final combine for expert 7
    combine_k<<<(BB * DOUT / 4) / 256, 256, 0, stream>>>(
        p0, p1, eb2 + (size_t)7 * DOUT, gat, 7, outC);
  }
}

// Round 6
// 1334.930 us; speedup vs baseline: 1.2906x; 1.2906x over previous
//
#include <hip/hip_runtime.h>
#include <hip/hip_bf16.h>
#include <stdint.h>

// B=8192, D_IN=1024, D_HID=4096, D_OUT=1024, E=8
#define BB 8192
#define DIN 1024
#define DHID 4096
#define DOUT 1024
#define NEXP 8
#define GH_N 2048  // D_HID/2

typedef __attribute__((ext_vector_type(8))) __bf16 bf16x8;
typedef __attribute__((ext_vector_type(4))) float f32x4;

__device__ inline unsigned short f2bf(float f) {
  unsigned u = __builtin_bit_cast(unsigned, f);
  u = (u + 0x7FFFu + ((u >> 16) & 1u)) >> 16;
  return (unsigned short)u;
}
__device__ inline float b2f(unsigned short s) {
  return __builtin_bit_cast(float, (unsigned)s << 16);
}

// ---------------- elementwise f32 -> bf16 ----------------
__global__ void cvt_f32_bf16(const float* __restrict__ in,
                             unsigned short* __restrict__ out, int n4) {
  int i = blockIdx.x * blockDim.x + threadIdx.x;
  if (i >= n4) return;
  float4 v = ((const float4*)in)[i];
  ushort4 o;
  o.x = f2bf(v.x); o.y = f2bf(v.y); o.z = f2bf(v.z); o.w = f2bf(v.w);
  ((ushort4*)out)[i] = o;
}

// ---------------- transpose + convert: in[R][C] f32 -> out[C][R] bf16 ----------------
__device__ inline void tr_tile(const float* __restrict__ in,
                               unsigned short* __restrict__ out, int R, int C,
                               int bx, int by) {
  __shared__ float tile[32][33];
  int c0 = bx * 32, r0 = by * 32;
  int tx = threadIdx.x & 31, ty = threadIdx.x >> 5;
#pragma unroll
  for (int i = 0; i < 4; ++i)
    tile[ty + i * 8][tx] = in[(size_t)(r0 + ty + i * 8) * C + c0 + tx];
  __syncthreads();
#pragma unroll
  for (int i = 0; i < 4; ++i)
    out[(size_t)(c0 + ty + i * 8) * R + r0 + tx] = f2bf(tile[tx][ty + i * 8]);
}

__global__ void transpose_cvt(const float* __restrict__ in,
                              unsigned short* __restrict__ out, int R, int C) {
  tr_tile(in, out, R, C, blockIdx.x, blockIdx.y);
}

// fused: W1 [1024][4096]->w1T and W2 [4096][1024]->w2T (expert 0 preload)
__global__ void transpose_cvt2(const float* __restrict__ w1,
                               unsigned short* __restrict__ w1T,
                               const float* __restrict__ w2,
                               unsigned short* __restrict__ w2T) {
  int b = blockIdx.x;
  if (b < 4096) {
    tr_tile(w1, w1T, DIN, DHID, b & 127, b >> 7);
  } else {
    b -= 4096;
    tr_tile(w2, w2T, DHID, DOUT, b & 31, b >> 5);
  }
}

// ---------------- async global->LDS 16B ----------------
__device__ inline void gload16(const void* g, void* l) {
  __builtin_amdgcn_global_load_lds(
      (const __attribute__((address_space(1))) void*)g,
      (__attribute__((address_space(3))) void*)l, 16, 0, 0);
}

template <int N>
__device__ inline void waitv() {
  if constexpr (N == 0) asm volatile("s_waitcnt vmcnt(0)" ::: "memory");
  else if constexpr (N == 2) asm volatile("s_waitcnt vmcnt(2)" ::: "memory");
  else if constexpr (N == 4) asm volatile("s_waitcnt vmcnt(4)" ::: "memory");
  else asm volatile("s_waitcnt vmcnt(0)" ::: "memory");
}
__device__ inline void waitlgkm0() {
  asm volatile("s_waitcnt lgkmcnt(0)" ::: "memory");
  __builtin_amdgcn_sched_barrier(0);
}
__device__ inline bf16x8 ldr(const char* p) { return *(const bf16x8*)p; }

// ---------------- unified fat GEMM core: 256x256 tile, 4-phase, BK=64 ------
// C = A[8192,K]*Bt[N,K]^T. 8 waves (2M x 4N), 2 LDS buffers, counted vmcnt.
// epi 0: outb = bf16(relu(acc+bias[col]))
// epi 1: outf (+)= gates[row*8+eidx]*(acc+bias[col])
// epi 2: split-K raw partial (ks = swz&1, k-offset ks*K, outf += ks*BB*N)
struct GArgs {
  const unsigned short* A;
  const unsigned short* Bt;
  int lda, ldb, N, K;
  const float* bias;
  unsigned short* outb;
  float* outf;
  const float* gates;
  int eidx, accum, epi, nb;
};

__device__ __forceinline__ void gemm_core(const GArgs& g, int local,
                                          char* Als, char* Bls) {
  constexpr int ABYTES = 32768, BBYTES = 32768;
  const int t = threadIdx.x;
  const int lane = t & 63;
  const int wid = t >> 6;
  const int wm = wid >> 2;
  const int wn = wid & 3;
  const int l15 = lane & 15, lg = lane >> 4;

  // bijective XCD swizzle within role (nb % 8 == 0 for all roles)
  const int nb = g.nb;
  const int swz = (local & 7) * (nb >> 3) + (local >> 3);
  int ks = 0, tid = swz;
  if (g.epi == 2) { ks = swz & 1; tid = swz >> 1; }
  const int nbn = g.N >> 8;
  const int bn = tid % nbn, bm = tid / nbn;
  const int m0 = bm * 256, n0 = bn * 256;
  const int kbase = ks * g.K;
  float* outf = g.outf;
  if (g.epi == 2) outf += (size_t)ks * ((size_t)BB * g.N);

  // stage source pointers (XOR chunk swizzle, involution shared with reads)
  const int prow = t >> 3;
  const int cOff = ((t & 7) ^ (prow & 7)) * 8;
  const unsigned short* aP[4];
  const unsigned short* bP[4];
#pragma unroll
  for (int u = 0; u < 4; ++u) {
    int p = u * 64 + prow;
    int ga = ((p >> 6) & 1) * 128 + ((p >> 7) & 1) * 64 + (p & 63);
    aP[u] = g.A + (size_t)(m0 + ga) * g.lda + kbase + cOff;
    int gb = ((p >> 5) & 3) * 64 + ((p >> 7) & 1) * 32 + (p & 31);
    bP[u] = g.Bt + (size_t)(n0 + gb) * g.ldb + kbase + cOff;
  }
  const int ldst = t * 16;

  // LDS read bases
  const int slot0 = ((lg) ^ (l15 & 7)) * 16;
  const int slot1 = ((4 + lg) ^ (l15 & 7)) * 16;
  const int aRB0 = (wm * 64 + l15) * 128;
  const int aRB1 = (128 + wm * 64 + l15) * 128;
  const int bCB0 = (wn * 32 + l15) * 128;
  const int bCB1 = (128 + wn * 32 + l15) * 128;

  f32x4 acc[8][4];
  const f32x4 zero = {0.f, 0.f, 0.f, 0.f};
#pragma unroll
  for (int i = 0; i < 8; ++i)
#pragma unroll
    for (int j = 0; j < 4; ++j) acc[i][j] = zero;

  bf16x8 ar[4][2], bc0[2][2], bc1[2][2];
  const int NT = g.K >> 6;

  // prologue: stage tile 0 in positional order, retire ph0-set
  gload16(bP[0], Bls + 0 * 8192 + ldst);
  gload16(bP[1], Bls + 1 * 8192 + ldst);
  gload16(aP[0], Als + 0 * 8192 + ldst);
  gload16(aP[1], Als + 1 * 8192 + ldst);
  gload16(bP[2], Bls + 2 * 8192 + ldst);
  gload16(bP[3], Bls + 3 * 8192 + ldst);
  gload16(aP[2], Als + 2 * 8192 + ldst);
  gload16(aP[3], Als + 3 * 8192 + ldst);
  waitv<4>();
  __builtin_amdgcn_s_barrier();

  for (int T = 0; T < NT; ++T) {
    const int buf = T & 1;
    const char* Ab = Als + buf * ABYTES;
    const char* Bb = Bls + buf * BBYTES;
    char* An = Als + (buf ^ 1) * ABYTES;
    char* Bn = Bls + (buf ^ 1) * BBYTES;
    const bool stg = (T + 1 < NT);
    const int kn = (T + 1) << 6;

    // ph0: read A rh0 + B ch0; stage B0,B1; mfma (rh0, cols 0-1)
#pragma unroll
    for (int f = 0; f < 4; ++f) {
      ar[f][0] = ldr(Ab + aRB0 + f * 2048 + slot0);
      ar[f][1] = ldr(Ab + aRB0 + f * 2048 + slot1);
    }
#pragma unroll
    for (int c = 0; c < 2; ++c) {
      bc0[c][0] = ldr(Bb + bCB0 + c * 2048 + slot0);
      bc0[c][1] = ldr(Bb + bCB0 + c * 2048 + slot1);
    }
    if (stg) {
      gload16(bP[0] + kn, Bn + 0 * 8192 + ldst);
      gload16(bP[1] + kn, Bn + 1 * 8192 + ldst);
    }
    __builtin_amdgcn_s_barrier();
    waitlgkm0();
    __builtin_amdgcn_s_setprio(1);
#pragma unroll
    for (int ksl = 0; ksl < 2; ++ksl)
#pragma unroll
      for (int f = 0; f < 4; ++f)
#pragma unroll
        for (int c = 0; c < 2; ++c)
          acc[f][c] = __builtin_amdgcn_mfma_f32_16x16x32_bf16(
              ar[f][ksl], bc0[c][ksl], acc[f][c], 0, 0, 0);
    __builtin_amdgcn_s_setprio(0);
    if (stg) waitv<4>(); else waitv<2>();
    __builtin_amdgcn_s_barrier();

    // ph1: read B ch1; stage A0,A1; mfma (rh0, cols 2-3)
#pragma unroll
    for (int c = 0; c < 2; ++c) {
      bc1[c][0] = ldr(Bb + bCB1 + c * 2048 + slot0);
      bc1[c][1] = ldr(Bb + bCB1 + c * 2048 + slot1);
    }
    if (stg) {
      gload16(aP[0] + kn, An + 0 * 8192 + ldst);
      gload16(aP[1] + kn, An + 1 * 8192 + ldst);
    }
    __builtin_amdgcn_s_barrier();
    waitlgkm0();
    __builtin_amdgcn_s_setprio(1);
#pragma unroll
    for (int ksl = 0; ksl < 2; ++ksl)
#pragma unroll
      for (int f = 0; f < 4; ++f)
#pragma unroll
        for (int c = 0; c < 2; ++c)
          acc[f][2 + c] = __builtin_amdgcn_mfma_f32_16x16x32_bf16(
              ar[f][ksl], bc1[c][ksl], acc[f][2 + c], 0, 0, 0);
    __builtin_amdgcn_s_setprio(0);
    if (stg) waitv<4>(); else waitv<0>();
    __builtin_amdgcn_s_barrier();

    // ph2: read A rh1; stage B2,B3; mfma (rh1, cols 2-3)
#pragma unroll
    for (int f = 0; f < 4; ++f) {
      ar[f][0] = ldr(Ab + aRB1 + f * 2048 + slot0);
      ar[f][1] = ldr(Ab + aRB1 + f * 2048 + slot1);
    }
    if (stg) {
      gload16(bP[2] + kn, Bn + 2 * 8192 + ldst);
      gload16(bP[3] + kn, Bn + 3 * 8192 + ldst);
    }
    __builtin_amdgcn_s_barrier();
    waitlgkm0();
    __builtin_amdgcn_s_setprio(1);
#pragma unroll
    for (int ksl = 0; ksl < 2; ++ksl)
#pragma unroll
      for (int f = 0; f < 4; ++f)
#pragma unroll
        for (int c = 0; c < 2; ++c)
          acc[4 + f][2 + c] = __builtin_amdgcn_mfma_f32_16x16x32_bf16(
              ar[f][ksl], bc1[c][ksl], acc[4 + f][2 + c], 0, 0, 0);
    __builtin_amdgcn_s_setprio(0);
    __builtin_amdgcn_s_barrier();

    // ph3: no ds_reads; stage A2,A3; mfma (rh1, cols 0-1)
    if (stg) {
      gload16(aP[2] + kn, An + 2 * 8192 + ldst);
      gload16(aP[3] + kn, An + 3 * 8192 + ldst);
    }
    __builtin_amdgcn_s_barrier();
    __builtin_amdgcn_s_setprio(1);
#pragma unroll
    for (int ksl = 0; ksl < 2; ++ksl)
#pragma unroll
      for (int f = 0; f < 4; ++f)
#pragma unroll
        for (int c = 0; c < 2; ++c)
          acc[4 + f][c] = __builtin_amdgcn_mfma_f32_16x16x32_bf16(
              ar[f][ksl], bc0[c][ksl], acc[4 + f][c], 0, 0, 0);
    __builtin_amdgcn_s_setprio(0);
    if (stg) waitv<4>();
    __builtin_amdgcn_s_barrier();
  }

  // epilogue: D row = lg*4 + reg (within 16), col = l15 (m89-verified)
  const int rb = m0 + wm * 128 + (lg << 2);
  const int cb = n0 + wn * 64 + l15;
  const int N = g.N;
  if (g.epi == 0) {
#pragma unroll
    for (int fg = 0; fg < 8; ++fg) {
#pragma unroll
      for (int j = 0; j < 4; ++j) {
        int col = cb + j * 16;
        float bv = g.bias[col];
#pragma unroll
        for (int r = 0; r < 4; ++r) {
          int row = rb + fg * 16 + r;
          float v = acc[fg][j][r] + bv;
          g.outb[(size_t)row * N + col] = f2bf(fmaxf(v, 0.f));
        }
      }
    }
  } else if (g.epi == 1) {
#pragma unroll
    for (int fg = 0; fg < 8; ++fg) {
      float gv[4];
#pragma unroll
      for (int r = 0; r < 4; ++r)
        gv[r] = g.gates[(size_t)(rb + fg * 16 + r) * NEXP + g.eidx];
#pragma unroll
      for (int j = 0; j < 4; ++j) {
        int col = cb + j * 16;
        float bv = g.bias[col];
#pragma unroll
        for (int r = 0; r < 4; ++r) {
          size_t o = (size_t)(rb + fg * 16 + r) * N + col;
          float v = (acc[fg][j][r] + bv) * gv[r];
          outf[o] = g.accum ? outf[o] + v : v;
        }
      }
    }
  } else {
#pragma unroll
    for (int fg = 0; fg < 8; ++fg) {
#pragma unroll
      for (int j = 0; j < 4; ++j) {
        int col = cb + j * 16;
#pragma unroll
        for (int r = 0; r < 4; ++r) {
          size_t o = (size_t)(rb + fg * 16 + r) * N + col;
          outf[o] = acc[fg][j][r];
        }
      }
    }
  }
}

// dual-role dispatch: blocks [0,nbA) run role a, rest run role b.
// Heavy role goes FIRST (LPT packing).
__global__ __launch_bounds__(512, 2)
void gemmU(GArgs a, GArgs b, int nbA) {
  __shared__ char lds[131072];
  const bool rA = (int)blockIdx.x < nbA;
  const GArgs& sel = rA ? a : b;
  const int local = rA ? (int)blockIdx.x : (int)blockIdx.x - nbA;
  gemm_core(sel, local, lds, lds + 65536);
}

// ---------------- standalone split-K combine (last expert) ----------------
__global__ void combine_k(const float* __restrict__ p0,
                          const float* __restrict__ p1,
                          const float* __restrict__ bias,
                          const float* __restrict__ gates, int eidx,
                          float* __restrict__ outC) {
  int i = blockIdx.x * blockDim.x + threadIdx.x;
  int r = i >> 8, c4 = i & 255;
  float g = gates[(size_t)r * NEXP + eidx];
  float4 a = ((const float4*)(p0 + (size_t)r * DOUT))[c4];
  float4 b = ((const float4*)(p1 + (size_t)r * DOUT))[c4];
  float4 bb = ((const float4*)bias)[c4];
  float4 p = ((const float4*)(outC + (size_t)r * DOUT))[c4];
  float4 o;
  o.x = p.x + g * (a.x + b.x + bb.x);
  o.y = p.y + g * (a.y + b.y + bb.y);
  o.z = p.z + g * (a.z + b.z + bb.z);
  o.w = p.w + g * (a.w + b.w + bb.w);
  ((float4*)(outC + (size_t)r * DOUT))[c4] = o;
}

// ---------------- gating head ----------------
__global__ __launch_bounds__(512)
void gating_head2(const unsigned short* __restrict__ gh,
                  const float* __restrict__ gW2,
                  const float* __restrict__ gb2,
                  float* __restrict__ gws,
                  float* __restrict__ g1,
                  float* __restrict__ g2) {
  __shared__ float wT[8][2048];
  const int t = threadIdx.x;
  for (int idx = t; idx < 16384; idx += 512) {
    wT[idx & 7][idx >> 3] = gW2[idx];
  }
  __syncthreads();
  const int wid = t >> 6, lane = t & 63;
  const int row = blockIdx.x * 8 + wid;
  const unsigned short* ghr = gh + (size_t)row * 2048;
  float s[8] = {0.f, 0.f, 0.f, 0.f, 0.f, 0.f, 0.f, 0.f};
#pragma unroll
  for (int j = 0; j < 8; ++j) {
    int k4 = lane + 64 * j;
    ushort4 hv = ((const ushort4*)ghr)[k4];
    float h0 = b2f(hv.x), h1 = b2f(hv.y), h2 = b2f(hv.z), h3 = b2f(hv.w);
#pragma unroll
    for (int e = 0; e < 8; ++e) {
      float4 w = ((const float4*)&wT[e][0])[k4];
      s[e] += h0 * w.x + h1 * w.y + h2 * w.z + h3 * w.w;
    }
  }
#pragma unroll
  for (int e = 0; e < 8; ++e)
#pragma unroll
    for (int off = 1; off < 64; off <<= 1) s[e] += __shfl_xor(s[e], off, 64);
  if (lane == 0) {
    float l[8], m = -1e30f;
#pragma unroll
    for (int e = 0; e < 8; ++e) {
      l[e] = s[e] + gb2[e];
      m = fmaxf(m, l[e]);
    }
    float sum = 0.f;
#pragma unroll
    for (int e = 0; e < 8; ++e) {
      l[e] = expf(l[e] - m);
      sum += l[e];
    }
    float inv = 1.f / sum;
#pragma unroll
    for (int e = 0; e < 8; ++e) {
      float gv = l[e] * inv;
      gws[(size_t)row * 8 + e] = gv;
      g1[(size_t)row * 8 + e] = gv;
      g2[(size_t)row * 8 + e] = gv;
    }
  }
}

extern "C" void kernel_launch(void* const* d_in, const int* in_sizes, int n_in,
                              void* d_out, int out_size, void* d_ws,
                              size_t ws_size, hipStream_t stream) {
  (void)in_sizes; (void)n_in; (void)out_size;
  const float* x   = (const float*)d_in[0];
  const float* gW1 = (const float*)d_in[1];
  const float* gb1 = (const float*)d_in[2];
  const float* gW2 = (const float*)d_in[3];
  const float* gb2 = (const float*)d_in[4];
  const float* eW1 = (const float*)d_in[5];
  const float* eb1 = (const float*)d_in[6];
  const float* eW2 = (const float*)d_in[7];
  const float* eb2 = (const float*)d_in[8];

  float* outC  = (float*)d_out;                       // [8192,1024]
  float* outG1 = outC + (size_t)BB * DOUT;            // [8192,8]
  float* outG2 = outG1 + (size_t)BB * NEXP;           // [8192,8]

  char* ws = (char*)d_ws;
  // layout (exactly 168,034,304 B -- proven available in r5):
  unsigned short* xb    = (unsigned short*)(ws);                 // 16 MB
  float*          gat   = (float*)(ws + 16777216);               // 256 KB
  unsigned short* w1T   = (unsigned short*)(ws + 17039360);      // 8 MB
  unsigned short* w2T   = (unsigned short*)(ws + 25427968);      // 8 MB
  unsigned short* hbufA = (unsigned short*)(ws + 33816576);      // 64 MB
  unsigned short* hbufB = (unsigned short*)(ws + 100925440);     // 64 MB
  unsigned short* gh    = hbufA;            // pre-loop alias (32 MB)
  unsigned short* gW1T  = hbufB;            // pre-loop alias (4 MB)
  float* p0 = (float*)hbufA;                // last-expert partials (2x32 MB)
  float* p1 = (float*)(ws + 33816576 + 33554432);
  const bool paired = ws_size >= (size_t)168034304;

  cvt_f32_bf16<<<(BB * DIN / 4) / 256, 256, 0, stream>>>(x, xb, BB * DIN / 4);
  transpose_cvt<<<dim3(GH_N / 32, DIN / 32), 256, 0, stream>>>(gW1, gW1T, DIN, GH_N);
  // gating GEMM: gh = relu(x @ gW1 + gb1)   grid 32*8=256
  {
    GArgs a{xb, gW1T, DIN, DIN, GH_N, DIN, gb1, gh, nullptr, nullptr, 0, 0, 0, 256};
    gemmU<<<256, 512, 0, stream>>>(a, a, 256);
  }
  gating_head2<<<BB / 8, 512, 0, stream>>>(gh, gW2, gb2, gat, outG1, outG2);

  // expert 0 weights
  transpose_cvt2<<<8192, 256, 0, stream>>>(eW1, w1T, eW2, w2T);
  // D0: G1(0) -> hbufA   grid 32*16=512
  {
    GArgs a{xb, w1T, DIN, DIN, DHID, DIN, eb1, hbufA, nullptr, nullptr, 0, 0, 0, 512};
    gemmU<<<512, 512, 0, stream>>>(a, a, 512);
  }

  for (int e = 0; e < 7; ++e) {
    // w1T(e+1)  (G1(e) already consumed w1T(e) in previous dispatch)
    transpose_cvt<<<dim3(DHID / 32, DIN / 32), 256, 0, stream>>>(
        eW1 + (size_t)(e + 1) * DIN * DHID, w1T, DIN, DHID);
    unsigned short* hcur = (e & 1) ? hbufB : hbufA;
    unsigned short* hnxt = paired ? ((e & 1) ? hbufA : hbufB) : hbufA;
    GArgs g2{hcur, w2T, DHID, DHID, DOUT, DHID, eb2 + (size_t)e * DOUT,
             nullptr, outC, gat, e, (e > 0) ? 1 : 0, 1, 128};
    GArgs g1{xb, w1T, DIN, DIN, DHID, DIN, eb1 + (size_t)(e + 1) * DHID,
             hnxt, nullptr, nullptr, 0, 0, 0, 512};
    if (paired) {
      // one 640-block dispatch: 128 heavy G2 blocks first, 512 G1 blocks fill
      gemmU<<<640, 512, 0, stream>>>(g2, g1, 128);
    } else {
      g2.A = hbufA; g1.outb = hbufA;
      gemmU<<<128, 512, 0, stream>>>(g2, g2, 128);
      gemmU<<<512, 512, 0, stream>>>(g1, g1, 512);
    }
    // w2T(e+1)  (G2(e) just consumed w2T(e))
    transpose_cvt<<<dim3(DOUT / 32, DHID / 32), 256, 0, stream>>>(
        eW2 + (size_t)(e + 1) * DHID * DOUT, w2T, DHID, DOUT);
  }

  if (paired) {
    // D8: G2(7) split-K x2 (full chip); h(7) in hbufB, partials in hbufA
    GArgs a{hbufB, w2T, DHID, DHID, DOUT, DHID / 2, nullptr, nullptr, p0,
            nullptr, 7, 0, 2, 256};
    gemmU<<<256, 512, 0, stream>>>(a, a, 256);
    combine_k<<<(BB * DOUT / 4) / 256, 256, 0, stream>>>(
        p0, p1, eb2 + (size_t)7 * DOUT, gat, 7, outC);
  } else {
    GArgs a{hbufA, w2T, DHID, DHID, DOUT, DHID, eb2 + (size_t)7 * DOUT,
            nullptr, outC, gat, 7, 1, 1, 128};
    gemmU<<<128, 512, 0, stream>>>(a, a, 128);
  }
}